// Round 22
// baseline (45.862 us; speedup 1.0000x reference)
//
#include <hip/hip_runtime.h>
#include <hip/hip_bf16.h>

typedef __bf16 bf16x8 __attribute__((ext_vector_type(8)));
typedef _Float16 f16x8 __attribute__((ext_vector_type(8)));
typedef _Float16 f16x2 __attribute__((ext_vector_type(2)));
typedef float f32x4 __attribute__((ext_vector_type(4)));

#define B_DIM 16
#define L_DIM 1024
#define H_DIM 4
#define HC 128
#define TI 32
#define WPITCH 136   // bf16 elems; 272B rows, 16B-aligned

// ---------------------------------------------------------------------------
// Kernel 1: projection via MFMA (R12-proven, byte-exact). bf16 hi/lo
// compensated core, fp16 outputs, x16 pre-scale for fp16 range.
// ---------------------------------------------------------------------------
__global__ __launch_bounds__(128) void proj_kernel(
    const float* __restrict__ x, const float* __restrict__ W,
    const float* __restrict__ bias, const float* __restrict__ att_src,
    const float* __restrict__ att_dst, _Float16* __restrict__ xpT,
    _Float16* __restrict__ E1h, _Float16* __restrict__ E2h,
    float* __restrict__ Rr)
{
  __shared__ __align__(16) __bf16 Wlds[128 * WPITCH];
  __shared__ __align__(16) __bf16 xh[32 * WPITCH];
  __shared__ __align__(16) __bf16 xl[32 * WPITCH];
  const int t = threadIdx.x;
  const int w = t >> 6;
  const int lane = t & 63;
  const int r0 = blockIdx.x * 32;

#pragma unroll
  for (int p = 0; p < 16; ++p) {
    const int idx = p * 1024 + t * 8;
    const int n = idx >> 7, k = idx & 127;
    const f32x4 a = *reinterpret_cast<const f32x4*>(W + idx);
    const f32x4 b = *reinterpret_cast<const f32x4*>(W + idx + 4);
    bf16x8 v;
#pragma unroll
    for (int e = 0; e < 4; ++e) { v[e] = (__bf16)a[e]; v[e + 4] = (__bf16)b[e]; }
    *reinterpret_cast<bf16x8*>(&Wlds[n * WPITCH + k]) = v;
  }
#pragma unroll
  for (int p = 0; p < 4; ++p) {
    const int idx = p * 1024 + t * 8;
    const int r = idx >> 7, k = idx & 127;
    const float* xp_ = x + (size_t)(r0 + r) * 128 + k;
    const f32x4 a = *reinterpret_cast<const f32x4*>(xp_);
    const f32x4 b = *reinterpret_cast<const f32x4*>(xp_ + 4);
    bf16x8 vh, vl;
#pragma unroll
    for (int e = 0; e < 4; ++e) {
      const float fa = a[e], fb = b[e];
      vh[e] = (__bf16)fa;          vh[e + 4] = (__bf16)fb;
      vl[e] = (__bf16)(fa - (float)vh[e]);
      vl[e + 4] = (__bf16)(fb - (float)vh[e + 4]);
    }
    *reinterpret_cast<bf16x8*>(&xh[r * WPITCH + k]) = vh;
    *reinterpret_cast<bf16x8*>(&xl[r * WPITCH + k]) = vl;
  }
  __syncthreads();

  const int rr = lane & 15;
  const int g8 = (lane >> 4) * 8;
  f32x4 acc[8] = {};
#pragma unroll
  for (int kk = 0; kk < 4; ++kk) {
    const int ko = kk * 32 + g8;
    const bf16x8 bh = *reinterpret_cast<const bf16x8*>(&xh[(w * 16 + rr) * WPITCH + ko]);
    const bf16x8 bl = *reinterpret_cast<const bf16x8*>(&xl[(w * 16 + rr) * WPITCH + ko]);
#pragma unroll
    for (int nc = 0; nc < 8; ++nc) {
      const bf16x8 af = *reinterpret_cast<const bf16x8*>(&Wlds[(nc * 16 + rr) * WPITCH + ko]);
      acc[nc] = __builtin_amdgcn_mfma_f32_16x16x32_bf16(af, bh, acc[nc], 0, 0, 0);
      acc[nc] = __builtin_amdgcn_mfma_f32_16x16x32_bf16(af, bl, acc[nc], 0, 0, 0);
    }
  }

  const int q4 = (lane >> 4) * 4;
  const int grow = r0 + w * 16 + rr;
  const int bb = grow >> 10;
  const int lg = grow & 1023;
  float asum[4] = {0.f, 0.f, 0.f, 0.f};
  float adsum[4] = {0.f, 0.f, 0.f, 0.f};
#pragma unroll
  for (int nc = 0; nc < 8; ++nc) {
    const int n0 = nc * 16 + q4;
    const f32x4 bv = *reinterpret_cast<const f32x4*>(bias + n0);
    const f32x4 sv = *reinterpret_cast<const f32x4*>(att_src + n0);
    const f32x4 dv = *reinterpret_cast<const f32x4*>(att_dst + n0);
    const int h = nc >> 1;
#pragma unroll
    for (int reg = 0; reg < 4; ++reg) {
      const float v = acc[nc][reg] + bv[reg];
      const int n = n0 + reg;
      xpT[((size_t)bb * 128 + n) * 1024 + lg] = (_Float16)v;
      asum[h]  = fmaf(v, sv[reg], asum[h]);
      adsum[h] = fmaf(v, dv[reg], adsum[h]);
    }
  }
#pragma unroll
  for (int h = 0; h < 4; ++h) {
    asum[h]  += __shfl_xor(asum[h], 16);
    asum[h]  += __shfl_xor(asum[h], 32);
    adsum[h] += __shfl_xor(adsum[h], 16);
    adsum[h] += __shfl_xor(adsum[h], 32);
  }
  if ((lane >> 4) == 0) {
#pragma unroll
    for (int h = 0; h < 4; ++h) {
      const size_t o = ((size_t)bb * 4 + h) * 1024 + lg;
      E1h[o] = (_Float16)(16.0f * __expf(asum[h]));
      E2h[o] = (_Float16)__expf(0.2f * asum[h]);
      Rr[o]  = 16.0f * __expf(-0.8f * adsum[h]);
    }
  }
}

// ---------------------------------------------------------------------------
// Kernel 2 (flash attn, adj in-kernel, TI=32, 2 blocks/CU):
//   R21's chunk-pipelined structure at half tile: block = 32 rows, grid 512
//   -> 2 blocks/CU = 4 waves/SIMD (R11-proven latency-hiding regime).
//   Wave = (head h, row-half rh) owns ONE 16-row group over all 1024 j.
//   Per chunk of 128 j: { read masks (uint4/row from 1KB dbuf) -> pack next
//   chunk (8 bits -> byte/thread, diag folded) -> issue adj loads chunk+2
//   (2 int4/thread) -> 4 compute iters (3 MFMAs) -> barrier }.
//   launch_bounds(512,4): 128-reg budget, state ~100 regs.
// ---------------------------------------------------------------------------
__global__ __launch_bounds__(512, 4) void gat_attn_kernel(
    const int* __restrict__ adj, const _Float16* __restrict__ xpT,
    const _Float16* __restrict__ E1h, const _Float16* __restrict__ E2h,
    const float* __restrict__ Rr, float* __restrict__ out)
{
  __shared__ __align__(16) unsigned e1u[H_DIM][512];          // 8 KB
  __shared__ __align__(16) unsigned e2u[H_DIM][512];          // 8 KB
  __shared__ __align__(16) unsigned char msk[2][32][16];      // 1 KB dbuf

  const int wg  = blockIdx.x;     // 512 blocks
  const int xcd = wg & 7;
  const int idx = wg >> 3;        // 0..63 per XCD
  const int b   = xcd * 2 + (idx & 1);
  const int i0  = (idx >> 1) * TI;

  const int t = threadIdx.x;
  const int wv = t >> 6;        // 0..7
  const int lane = t & 63;
  const int h  = wv >> 1;       // head
  const int rh = wv & 1;        // row-half (16 rows)
  const int ln15 = lane & 15;
  const int kh = lane >> 4;
  const int jb = kh * 8;

  // ---- adj pack mapping: thread (row pr 0..31, 8-j seg ps 0..15) ----
  const int pr = t >> 4;
  const int ps = t & 15;
  const int gi = i0 + pr;
  const int* arow = adj + ((size_t)b * L_DIM + gi) * L_DIM + ps * 8;

  int4 av[2];                   // raw adj for one 8-j segment (32B)
#define LOAD_CHUNK(c)                                                    \
  {                                                                      \
    av[0] = *reinterpret_cast<const int4*>(arow + (c) * 128);            \
    av[1] = *reinterpret_cast<const int4*>(arow + (c) * 128 + 4);        \
  }
#define PACK_CHUNK(c, buf)                                               \
  {                                                                      \
    const int4 u = av[0], w2 = av[1];                                    \
    unsigned bits = (unsigned)u.x | ((unsigned)u.y << 1) |               \
                    ((unsigned)u.z << 2) | ((unsigned)u.w << 3) |        \
                    ((unsigned)w2.x << 4) | ((unsigned)w2.y << 5) |      \
                    ((unsigned)w2.z << 6) | ((unsigned)w2.w << 7);       \
    const int d = gi - ((c) * 128 + ps * 8);                             \
    if ((unsigned)d < 8u) bits |= (1u << d);                             \
    msk[buf][pr][ps] = (unsigned char)bits;                              \
  }

  // ---- prologue: chunk0 load+pack, chunk1 load; e1/e2 staging ----
  LOAD_CHUNK(0);
  {
    const int sh = t >> 7;          // head for staging
    const int off = (t & 127) * 8;  // f16 elems
    const _Float16* p1 = E1h + ((size_t)(b * H_DIM + sh)) * L_DIM + off;
    const _Float16* p2 = E2h + ((size_t)(b * H_DIM + sh)) * L_DIM + off;
    *reinterpret_cast<uint4*>(&e1u[sh][off >> 1]) = *reinterpret_cast<const uint4*>(p1);
    *reinterpret_cast<uint4*>(&e2u[sh][off >> 1]) = *reinterpret_cast<const uint4*>(p2);
  }
  PACK_CHUNK(0, 0);
  LOAD_CHUNK(1);

  const float Rv = Rr[((size_t)(b * H_DIM + h)) * L_DIM + i0 + rh * 16 + ln15];
  const _Float16 rv16 = (_Float16)Rv;
  const f16x2 R2 = {rv16, rv16};
  const _Float16* xb0 = xpT + ((size_t)(b * 128 + h * 32 + ln15)) * 1024;
  const _Float16* xb1 = xb0 + 16 * 1024;

  // 4-deep xpT ring (issued before barrier: L2 latency hides under it)
  uint4 pf0[4], pf1[4];
#pragma unroll
  for (int s = 0; s < 4; ++s) {
    pf0[s] = *reinterpret_cast<const uint4*>(xb0 + s * 32 + jb);
    pf1[s] = *reinterpret_cast<const uint4*>(xb1 + s * 32 + jb);
  }
  __syncthreads();   // e1/e2 + msk chunk0 visible

  uint4 u1r[2], u2r[2];
#pragma unroll
  for (int s = 0; s < 2; ++s) {
    const int ke = (s * 32 + jb) >> 1;
    u1r[s] = *reinterpret_cast<const uint4*>(&e1u[h][ke]);
    u2r[s] = *reinterpret_cast<const uint4*>(&e2u[h][ke]);
  }

  f32x4 acc0 = {}, acc1 = {}, accS = {};
  f16x8 ones16;
#pragma unroll
  for (int e = 0; e < 8; ++e) ones16[e] = (_Float16)1.0f;

  int cbuf = 0;
  for (int c = 0; c < 8; ++c) {
    // step 1: this chunk's mask words (uint4 = 128 bits for owned row)
    uint4 mwc = *reinterpret_cast<const uint4*>(&msk[cbuf][rh * 16 + ln15][0]);
    // step 2: pack next chunk into the other buffer (av holds chunk c+1)
    if (c < 7) PACK_CHUNK(c + 1, cbuf ^ 1);
    // step 3: issue adj loads for chunk c+2
    if (c < 6) LOAD_CHUNK(c + 2);

    // step 4: 4 compute iters (static ring slots: it, it&1)
#pragma unroll
    for (int it = 0; it < 4; ++it) {
      const int kr = c * 128 + it * 32;
      const unsigned w32 = (it == 0) ? mwc.x : (it == 1) ? mwc.y
                         : (it == 2) ? mwc.z : mwc.w;
      const unsigned mb = (w32 >> (kh * 8)) & 0xffu;

      // e-ring: consume slot it&1, refill +64 (wrap keeps addr in-bounds)
      const uint4 u1c = u1r[it & 1];
      const uint4 u2c = u2r[it & 1];
      const int kn = (((kr + 64) & 1023) + jb) >> 1;
      u1r[it & 1] = *reinterpret_cast<const uint4*>(&e1u[h][kn]);
      u2r[it & 1] = *reinterpret_cast<const uint4*>(&e2u[h][kn]);

      // xpT ring: consume slot it, refill +128 (over-read lands in ws)
      const uint4 bb0 = pf0[it];
      const uint4 bb1 = pf1[it];
      pf0[it] = *reinterpret_cast<const uint4*>(xb0 + kr + 128 + jb);
      pf1[it] = *reinterpret_cast<const uint4*>(xb1 + kr + 128 + jb);

      const unsigned uu1[4] = {u1c.x, u1c.y, u1c.z, u1c.w};
      const unsigned uu2[4] = {u2c.x, u2c.y, u2c.z, u2c.w};
      unsigned rg[4];
#pragma unroll
      for (int q = 0; q < 4; ++q) {
        f16x2 a, ee;
        __builtin_memcpy(&a,  &uu1[q], 4);
        __builtin_memcpy(&ee, &uu2[q], 4);
        const f16x2 pr2 = ee * R2;                          // v_pk_mul_f16
        const f16x2 mx = __builtin_elementwise_max(a, pr2); // v_pk_max_f16
        unsigned mu;
        __builtin_memcpy(&mu, &mx, 4);
        const unsigned mlo = (mb & (1u << (2 * q)))     ? 0xFFFFu : 0u;
        const unsigned mhi = (mb & (1u << (2 * q + 1))) ? 0xFFFF0000u : 0u;
        rg[q] = mu & (mlo | mhi);
      }
      f16x8 af, b0h, b1h;
      const uint4 afu = {rg[0], rg[1], rg[2], rg[3]};
      __builtin_memcpy(&af,  &afu, 16);
      __builtin_memcpy(&b0h, &bb0, 16);
      __builtin_memcpy(&b1h, &bb1, 16);
      __builtin_amdgcn_s_setprio(1);
      acc0 = __builtin_amdgcn_mfma_f32_16x16x32_f16(af, b0h, acc0, 0, 0, 0);
      acc1 = __builtin_amdgcn_mfma_f32_16x16x32_f16(af, b1h, acc1, 0, 0, 0);
      accS = __builtin_amdgcn_mfma_f32_16x16x32_f16(af, ones16, accS, 0, 0, 0);
      __builtin_amdgcn_s_setprio(0);
    }
    __syncthreads();   // pack complete + mask reads done before buffer reuse
    cbuf ^= 1;
  }

  // ---- epilogue: wave owns complete rows -> direct normalize + store ----
#pragma unroll
  for (int reg = 0; reg < 4; ++reg) {
    const float rs = 1.0f / accS[reg];
    const int row = i0 + rh * 16 + kh * 4 + reg;
    float* op = out + ((size_t)(b * L_DIM + row)) * HC + h * 32;
    op[ln15]      = acc0[reg] * rs;
    op[16 + ln15] = acc1[reg] * rs;
  }
#undef LOAD_CHUNK
#undef PACK_CHUNK
}

extern "C" void kernel_launch(void* const* d_in, const int* in_sizes, int n_in,
                              void* d_out, int out_size, void* d_ws, size_t ws_size,
                              hipStream_t stream) {
  (void)in_sizes; (void)n_in; (void)out_size; (void)ws_size;
  const float* x        = (const float*)d_in[0];
  const int*   adj      = (const int*)d_in[1];
  const float* W        = (const float*)d_in[2];
  const float* bias     = (const float*)d_in[3];
  const float* att_src  = (const float*)d_in[4];
  const float* att_dst  = (const float*)d_in[5];
  float* out = (float*)d_out;

  char* ws = (char*)d_ws;
  _Float16* xpT = (_Float16*)ws;                                    // 4 MiB
  _Float16* E1h = (_Float16*)(ws + (size_t)4 * 1024 * 1024);        // 128 KiB
  _Float16* E2h = (_Float16*)(ws + (size_t)4 * 1024 * 1024 + 131072);
  float*    Rr  = (float*)(ws + (size_t)4 * 1024 * 1024 + 262144);  // 256 KiB

  hipLaunchKernelGGL(proj_kernel, dim3(B_DIM * L_DIM / 32), dim3(128), 0, stream,
                     x, W, bias, att_src, att_dst, xpT, E1h, E2h, Rr);
  hipLaunchKernelGGL(gat_attn_kernel, dim3(B_DIM * L_DIM / TI), dim3(512), 0, stream,
                     adj, xpT, E1h, E2h, Rr, out);
}

// Round 23
// 34.151 us; speedup vs baseline: 1.3429x; 1.3429x over previous
//
#include <hip/hip_runtime.h>
#include <hip/hip_bf16.h>

typedef __bf16 bf16x8 __attribute__((ext_vector_type(8)));
typedef _Float16 f16x8 __attribute__((ext_vector_type(8)));
typedef _Float16 f16x2 __attribute__((ext_vector_type(2)));
typedef float f32x4 __attribute__((ext_vector_type(4)));

#define B_DIM 16
#define L_DIM 1024
#define H_DIM 4
#define HC 128
#define TI 64
#define WPITCH 136   // bf16 elems; 272B rows, 16B-aligned

// ---------------------------------------------------------------------------
// Kernel 1: projection via MFMA (R12-proven, byte-exact). bf16 hi/lo
// compensated core, fp16 outputs, x16 pre-scale for fp16 range.
// ---------------------------------------------------------------------------
__global__ __launch_bounds__(128) void proj_kernel(
    const float* __restrict__ x, const float* __restrict__ W,
    const float* __restrict__ bias, const float* __restrict__ att_src,
    const float* __restrict__ att_dst, _Float16* __restrict__ xpT,
    _Float16* __restrict__ E1h, _Float16* __restrict__ E2h,
    float* __restrict__ Rr)
{
  __shared__ __align__(16) __bf16 Wlds[128 * WPITCH];
  __shared__ __align__(16) __bf16 xh[32 * WPITCH];
  __shared__ __align__(16) __bf16 xl[32 * WPITCH];
  const int t = threadIdx.x;
  const int w = t >> 6;
  const int lane = t & 63;
  const int r0 = blockIdx.x * 32;

#pragma unroll
  for (int p = 0; p < 16; ++p) {
    const int idx = p * 1024 + t * 8;
    const int n = idx >> 7, k = idx & 127;
    const f32x4 a = *reinterpret_cast<const f32x4*>(W + idx);
    const f32x4 b = *reinterpret_cast<const f32x4*>(W + idx + 4);
    bf16x8 v;
#pragma unroll
    for (int e = 0; e < 4; ++e) { v[e] = (__bf16)a[e]; v[e + 4] = (__bf16)b[e]; }
    *reinterpret_cast<bf16x8*>(&Wlds[n * WPITCH + k]) = v;
  }
#pragma unroll
  for (int p = 0; p < 4; ++p) {
    const int idx = p * 1024 + t * 8;
    const int r = idx >> 7, k = idx & 127;
    const float* xp_ = x + (size_t)(r0 + r) * 128 + k;
    const f32x4 a = *reinterpret_cast<const f32x4*>(xp_);
    const f32x4 b = *reinterpret_cast<const f32x4*>(xp_ + 4);
    bf16x8 vh, vl;
#pragma unroll
    for (int e = 0; e < 4; ++e) {
      const float fa = a[e], fb = b[e];
      vh[e] = (__bf16)fa;          vh[e + 4] = (__bf16)fb;
      vl[e] = (__bf16)(fa - (float)vh[e]);
      vl[e + 4] = (__bf16)(fb - (float)vh[e + 4]);
    }
    *reinterpret_cast<bf16x8*>(&xh[r * WPITCH + k]) = vh;
    *reinterpret_cast<bf16x8*>(&xl[r * WPITCH + k]) = vl;
  }
  __syncthreads();

  const int rr = lane & 15;
  const int g8 = (lane >> 4) * 8;
  f32x4 acc[8] = {};
#pragma unroll
  for (int kk = 0; kk < 4; ++kk) {
    const int ko = kk * 32 + g8;
    const bf16x8 bh = *reinterpret_cast<const bf16x8*>(&xh[(w * 16 + rr) * WPITCH + ko]);
    const bf16x8 bl = *reinterpret_cast<const bf16x8*>(&xl[(w * 16 + rr) * WPITCH + ko]);
#pragma unroll
    for (int nc = 0; nc < 8; ++nc) {
      const bf16x8 af = *reinterpret_cast<const bf16x8*>(&Wlds[(nc * 16 + rr) * WPITCH + ko]);
      acc[nc] = __builtin_amdgcn_mfma_f32_16x16x32_bf16(af, bh, acc[nc], 0, 0, 0);
      acc[nc] = __builtin_amdgcn_mfma_f32_16x16x32_bf16(af, bl, acc[nc], 0, 0, 0);
    }
  }

  const int q4 = (lane >> 4) * 4;
  const int grow = r0 + w * 16 + rr;
  const int bb = grow >> 10;
  const int lg = grow & 1023;
  float asum[4] = {0.f, 0.f, 0.f, 0.f};
  float adsum[4] = {0.f, 0.f, 0.f, 0.f};
#pragma unroll
  for (int nc = 0; nc < 8; ++nc) {
    const int n0 = nc * 16 + q4;
    const f32x4 bv = *reinterpret_cast<const f32x4*>(bias + n0);
    const f32x4 sv = *reinterpret_cast<const f32x4*>(att_src + n0);
    const f32x4 dv = *reinterpret_cast<const f32x4*>(att_dst + n0);
    const int h = nc >> 1;
#pragma unroll
    for (int reg = 0; reg < 4; ++reg) {
      const float v = acc[nc][reg] + bv[reg];
      const int n = n0 + reg;
      xpT[((size_t)bb * 128 + n) * 1024 + lg] = (_Float16)v;
      asum[h]  = fmaf(v, sv[reg], asum[h]);
      adsum[h] = fmaf(v, dv[reg], adsum[h]);
    }
  }
#pragma unroll
  for (int h = 0; h < 4; ++h) {
    asum[h]  += __shfl_xor(asum[h], 16);
    asum[h]  += __shfl_xor(asum[h], 32);
    adsum[h] += __shfl_xor(adsum[h], 16);
    adsum[h] += __shfl_xor(adsum[h], 32);
  }
  if ((lane >> 4) == 0) {
#pragma unroll
    for (int h = 0; h < 4; ++h) {
      const size_t o = ((size_t)bb * 4 + h) * 1024 + lg;
      E1h[o] = (_Float16)(16.0f * __expf(asum[h]));
      E2h[o] = (_Float16)__expf(0.2f * asum[h]);
      Rr[o]  = 16.0f * __expf(-0.8f * adsum[h]);
    }
  }
}

// ---------------------------------------------------------------------------
// Kernel 2 (flash attn, adj streamed IN-KERNEL, chunk-pipelined) — R21-exact,
// the measured optimum (34.1us total). Wave = (head h, row-half rh) sweeps
// all 1024 j for 2 row-groups. j in 8 chunks of 128: { read masks (uint4/row
// from 2KB dbuf LDS) -> pack NEXT chunk from regs -> issue adj loads chunk+2
// -> 4 compute iters (6 MFMAs) -> barrier }. launch_bounds(512,2): 256-reg
// budget — the healthy side of the allocator cliff (64-VGPR mode at any
// >=4 waves/SIMD request is fatal: R10/R13/R19/R22).
// ---------------------------------------------------------------------------
__global__ __launch_bounds__(512, 2) void gat_attn_kernel(
    const int* __restrict__ adj, const _Float16* __restrict__ xpT,
    const _Float16* __restrict__ E1h, const _Float16* __restrict__ E2h,
    const float* __restrict__ Rr, float* __restrict__ out)
{
  __shared__ __align__(16) unsigned e1u[H_DIM][512];          // 8 KB
  __shared__ __align__(16) unsigned e2u[H_DIM][512];          // 8 KB
  __shared__ __align__(16) unsigned short msk[2][64][8];      // 2 KB dbuf

  const int wg  = blockIdx.x;     // 256 blocks
  const int xcd = wg & 7;
  const int idx = wg >> 3;
  const int b   = xcd * 2 + (idx & 1);
  const int i0  = (idx >> 1) * TI;

  const int t = threadIdx.x;
  const int wv = t >> 6;        // 0..7
  const int lane = t & 63;
  const int h  = wv >> 1;       // head
  const int rh = wv & 1;        // row-half
  const int ln15 = lane & 15;
  const int kh = lane >> 4;
  const int jb = kh * 8;

  // ---- adj pack mapping: thread (row pr, 16-j seg ps) ----
  const int pr = t >> 3;        // 0..63
  const int ps = t & 7;         // 0..7
  const int gi = i0 + pr;
  const int* arow = adj + ((size_t)b * L_DIM + gi) * L_DIM + ps * 16;

  int4 av[4];                   // raw adj for one 16-j segment (64B)
#define LOAD_CHUNK(c)                                                    \
  {                                                                      \
    _Pragma("unroll")                                                    \
    for (int q = 0; q < 4; ++q)                                          \
      av[q] = *reinterpret_cast<const int4*>(arow + (c) * 128 + q * 4);  \
  }
#define PACK_CHUNK(c, buf)                                               \
  {                                                                      \
    unsigned bits = 0;                                                   \
    _Pragma("unroll")                                                    \
    for (int q = 0; q < 4; ++q) {                                        \
      const int4 u = av[q];                                              \
      const unsigned b4 = (unsigned)u.x | ((unsigned)u.y << 1) |         \
                          ((unsigned)u.z << 2) | ((unsigned)u.w << 3);   \
      bits |= b4 << (q * 4);                                             \
    }                                                                    \
    const int d = gi - ((c) * 128 + ps * 16);                            \
    if ((unsigned)d < 16u) bits |= (1u << d);                            \
    msk[buf][pr][ps] = (unsigned short)bits;                             \
  }

  // ---- prologue: chunk0 load+pack, chunk1 load; e1/e2 staging ----
  LOAD_CHUNK(0);
  {
    const int sh = t >> 7;          // head for staging
    const int off = (t & 127) * 8;  // f16 elems
    const _Float16* p1 = E1h + ((size_t)(b * H_DIM + sh)) * L_DIM + off;
    const _Float16* p2 = E2h + ((size_t)(b * H_DIM + sh)) * L_DIM + off;
    *reinterpret_cast<uint4*>(&e1u[sh][off >> 1]) = *reinterpret_cast<const uint4*>(p1);
    *reinterpret_cast<uint4*>(&e2u[sh][off >> 1]) = *reinterpret_cast<const uint4*>(p2);
  }
  PACK_CHUNK(0, 0);
  LOAD_CHUNK(1);

  const float* RrB = Rr + ((size_t)(b * H_DIM + h)) * L_DIM + i0 + rh * 32 + ln15;
  f16x2 R2g[2];
#pragma unroll
  for (int g = 0; g < 2; ++g) {
    const _Float16 rv = (_Float16)RrB[g * 16];
    R2g[g][0] = rv; R2g[g][1] = rv;
  }
  const _Float16* xb0 = xpT + ((size_t)(b * 128 + h * 32 + ln15)) * 1024;
  const _Float16* xb1 = xb0 + 16 * 1024;

  // 4-deep xpT ring + 2-deep e ring (issue before barrier: hides under it)
  uint4 pf0[4], pf1[4];
#pragma unroll
  for (int s = 0; s < 4; ++s) {
    pf0[s] = *reinterpret_cast<const uint4*>(xb0 + s * 32 + jb);
    pf1[s] = *reinterpret_cast<const uint4*>(xb1 + s * 32 + jb);
  }
  __syncthreads();   // e1/e2 + msk chunk0 visible

  uint4 u1r[2], u2r[2];
#pragma unroll
  for (int s = 0; s < 2; ++s) {
    const int ke = (s * 32 + jb) >> 1;
    u1r[s] = *reinterpret_cast<const uint4*>(&e1u[h][ke]);
    u2r[s] = *reinterpret_cast<const uint4*>(&e2u[h][ke]);
  }

  f32x4 acc0[2] = {}, acc1[2] = {}, accS[2] = {};
  f16x8 ones16;
#pragma unroll
  for (int e = 0; e < 8; ++e) ones16[e] = (_Float16)1.0f;

  int cbuf = 0;
  for (int c = 0; c < 8; ++c) {
    // step 1: this chunk's mask words (1 uint4 per owned row)
    uint4 mwcA = *reinterpret_cast<const uint4*>(&msk[cbuf][rh * 32 + ln15][0]);
    uint4 mwcB = *reinterpret_cast<const uint4*>(&msk[cbuf][rh * 32 + 16 + ln15][0]);
    // step 2: pack next chunk into the other buffer (av holds chunk c+1)
    if (c < 7) PACK_CHUNK(c + 1, cbuf ^ 1);
    // step 3: issue adj loads for chunk c+2
    if (c < 6) LOAD_CHUNK(c + 2);

    // step 4: 4 compute iters (static ring slots: it, it&1)
#pragma unroll
    for (int it = 0; it < 4; ++it) {
      const int kr = c * 128 + it * 32;
      const unsigned wA = (it == 0) ? mwcA.x : (it == 1) ? mwcA.y
                        : (it == 2) ? mwcA.z : mwcA.w;
      const unsigned wB = (it == 0) ? mwcB.x : (it == 1) ? mwcB.y
                        : (it == 2) ? mwcB.z : mwcB.w;
      unsigned mb[2];
      mb[0] = (wA >> (kh * 8)) & 0xffu;
      mb[1] = (wB >> (kh * 8)) & 0xffu;

      // e-ring: consume slot it&1, refill +64 (wrap keeps addr in-bounds)
      const uint4 u1c = u1r[it & 1];
      const uint4 u2c = u2r[it & 1];
      const int kn = (((kr + 64) & 1023) + jb) >> 1;
      u1r[it & 1] = *reinterpret_cast<const uint4*>(&e1u[h][kn]);
      u2r[it & 1] = *reinterpret_cast<const uint4*>(&e2u[h][kn]);

      // xpT ring: consume slot it, refill +128 (over-read lands in ws)
      const uint4 bb0 = pf0[it];
      const uint4 bb1 = pf1[it];
      pf0[it] = *reinterpret_cast<const uint4*>(xb0 + kr + 128 + jb);
      pf1[it] = *reinterpret_cast<const uint4*>(xb1 + kr + 128 + jb);

      const unsigned uu1[4] = {u1c.x, u1c.y, u1c.z, u1c.w};
      const unsigned uu2[4] = {u2c.x, u2c.y, u2c.z, u2c.w};
      unsigned rg[2][4];
#pragma unroll
      for (int q = 0; q < 4; ++q) {
        f16x2 a, ee;
        __builtin_memcpy(&a,  &uu1[q], 4);
        __builtin_memcpy(&ee, &uu2[q], 4);
#pragma unroll
        for (int g = 0; g < 2; ++g) {
          const f16x2 pr2 = ee * R2g[g];                        // v_pk_mul_f16
          const f16x2 mx = __builtin_elementwise_max(a, pr2);   // v_pk_max_f16
          unsigned mu;
          __builtin_memcpy(&mu, &mx, 4);
          const unsigned mlo = (mb[g] & (1u << (2 * q)))     ? 0xFFFFu : 0u;
          const unsigned mhi = (mb[g] & (1u << (2 * q + 1))) ? 0xFFFF0000u : 0u;
          rg[g][q] = mu & (mlo | mhi);
        }
      }
      f16x8 b0h, b1h;
      __builtin_memcpy(&b0h, &bb0, 16);
      __builtin_memcpy(&b1h, &bb1, 16);
      __builtin_amdgcn_s_setprio(1);
#pragma unroll
      for (int g = 0; g < 2; ++g) {
        const uint4 afu = {rg[g][0], rg[g][1], rg[g][2], rg[g][3]};
        f16x8 af;
        __builtin_memcpy(&af, &afu, 16);
        acc0[g] = __builtin_amdgcn_mfma_f32_16x16x32_f16(af, b0h, acc0[g], 0, 0, 0);
        acc1[g] = __builtin_amdgcn_mfma_f32_16x16x32_f16(af, b1h, acc1[g], 0, 0, 0);
        accS[g] = __builtin_amdgcn_mfma_f32_16x16x32_f16(af, ones16, accS[g], 0, 0, 0);
      }
      __builtin_amdgcn_s_setprio(0);
    }
    __syncthreads();   // pack complete + mask reads done before buffer reuse
    cbuf ^= 1;
  }

  // ---- epilogue: waves own complete rows -> direct normalize + store ----
#pragma unroll
  for (int g = 0; g < 2; ++g) {
#pragma unroll
    for (int reg = 0; reg < 4; ++reg) {
      const float rs = 1.0f / accS[g][reg];
      const int row = i0 + rh * 32 + g * 16 + kh * 4 + reg;
      float* op = out + ((size_t)(b * L_DIM + row)) * HC + h * 32;
      op[ln15]      = acc0[g][reg] * rs;
      op[16 + ln15] = acc1[g][reg] * rs;
    }
  }
#undef LOAD_CHUNK
#undef PACK_CHUNK
}

extern "C" void kernel_launch(void* const* d_in, const int* in_sizes, int n_in,
                              void* d_out, int out_size, void* d_ws, size_t ws_size,
                              hipStream_t stream) {
  (void)in_sizes; (void)n_in; (void)out_size; (void)ws_size;
  const float* x        = (const float*)d_in[0];
  const int*   adj      = (const int*)d_in[1];
  const float* W        = (const float*)d_in[2];
  const float* bias     = (const float*)d_in[3];
  const float* att_src  = (const float*)d_in[4];
  const float* att_dst  = (const float*)d_in[5];
  float* out = (float*)d_out;

  char* ws = (char*)d_ws;
  _Float16* xpT = (_Float16*)ws;                                    // 4 MiB
  _Float16* E1h = (_Float16*)(ws + (size_t)4 * 1024 * 1024);        // 128 KiB
  _Float16* E2h = (_Float16*)(ws + (size_t)4 * 1024 * 1024 + 131072);
  float*    Rr  = (float*)(ws + (size_t)4 * 1024 * 1024 + 262144);  // 256 KiB

  hipLaunchKernelGGL(proj_kernel, dim3(B_DIM * L_DIM / 32), dim3(128), 0, stream,
                     x, W, bias, att_src, att_dst, xpT, E1h, E2h, Rr);
  hipLaunchKernelGGL(gat_attn_kernel, dim3(B_DIM * L_DIM / TI), dim3(512), 0, stream,
                     adj, xpT, E1h, E2h, Rr, out);
}